// Round 10
// baseline (603.325 us; speedup 1.0000x reference)
//
#include <hip/hip_runtime.h>
#include <hip/hip_cooperative_groups.h>
#include <cstdint>
#include <cstddef>

namespace cg = cooperative_groups;

constexpr int B_ROWS = 128;
constexpr int N_COLS = 65536;
constexpr int CAP    = 4096;       // per-row candidate capacity (expected ~1.8k)
constexpr int TPB    = 256;
constexpr int VB1    = 1024;       // virtual blocks for P1/P3
constexpr int SEGS   = VB1 / B_ROWS;          // 8 per row
constexpr int SEG_ELEMS = N_COLS / SEGS;      // 8192
constexpr int ITERS  = SEG_ELEMS / (TPB * 4); // 8
constexpr int CAND_SH = 4096;      // LDS candidate buffer per virtual block

// ---- ws layout (bytes) ----
constexpr size_t OFF_SLABCNT = 0;                        // int[1024][2048]  8MB
constexpr size_t OFF_SLABNP  = (size_t)8 << 20;          // int[1024]
constexpr size_t OFF_SLABSP  = ((size_t)8 << 20) + 4096; // float[1024]
constexpr size_t OFF_CAND    = (size_t)9 << 20;          // uint[128][4096]  2MB
constexpr size_t OFF_MISC    = (size_t)12 << 20;
constexpr size_t MO_NUMPOS   = 0;      // int[128]
constexpr size_t MO_SPOS     = 512;    // float[128]
constexpr size_t MO_CANDBIN  = 1024;   // int[128]
constexpr size_t MO_R1       = 1536;   // int[128]
constexpr size_t MO_KARR     = 2048;   // int[128]
constexpr size_t MO_CANDCNT  = 2560;   // int[128]
constexpr size_t MO_SABOVE   = 3072;   // float[128]
constexpr size_t MO_AUTO64   = 3584;   // ull[128]
constexpr size_t MO_GNUM     = 4608;   // double
constexpr size_t MO_GDEN     = 4616;   // int

// ---- monotone key <-> pred ----
__device__ __forceinline__ unsigned key_from_pred(float x) {
  unsigned b = __float_as_uint(x);
  return (b & 0x80000000u) ? ~b : (b | 0x80000000u);
}
__device__ __forceinline__ float pred_from_key(unsigned k) {
  unsigned b = (k & 0x80000000u) ? (k ^ 0x80000000u) : ~k;
  return __uint_as_float(b);
}

// ---- elementwise losses (validated absmax=0.0 R1/R3/R5/R8) ----
__device__ __forceinline__ float neg_loss(float x) {
  float ax = fabsf(x);
  float e  = expf(-ax);
  float p  = (x >= 0.0f) ? 1.0f / (1.0f + e) : e / (1.0f + e);
  float sp = fmaxf(x, 0.0f) + log1pf(e);
  float f  = p;
  float l  = sp * f * f * 0.25f;
  return (p >= 0.5f) ? l * 3.0f : l;
}
__device__ __forceinline__ float pos_loss(float x) {
  float ax = fabsf(x);
  float e  = expf(-ax);
  float p  = (x >= 0.0f) ? 1.0f / (1.0f + e) : e / (1.0f + e);
  float sp = fmaxf(-x, 0.0f) + log1pf(e);
  float f  = 1.0f - p;
  float l  = sp * f * f * 0.75f;
  return (p < 0.5f) ? l * 3.0f : l;
}
__device__ __forceinline__ float loss_from_key(unsigned k) { return neg_loss(pred_from_key(k)); }

// ---- two-level inclusive suffix scan over M = CH*TPB bins, (cnt,loss) pairs ----
__device__ void suffix_scan_2l(int* c, float* l, int M, int* tmpc, float* tmpl) {
  const int t = threadIdx.x;
  const int CH = M / TPB;
  int cs = 0; float ls = 0.0f;
  for (int j = 0; j < CH; ++j) { cs += c[t * CH + j]; ls += l[t * CH + j]; }
  tmpc[t] = cs; tmpl[t] = ls;
  __syncthreads();
  for (int d = 1; d < TPB; d <<= 1) {
    int v = tmpc[t] + ((t + d < TPB) ? tmpc[t + d] : 0);
    float w = tmpl[t] + ((t + d < TPB) ? tmpl[t + d] : 0.0f);
    __syncthreads();
    tmpc[t] = v; tmpl[t] = w;
    __syncthreads();
  }
  int runc = (t + 1 < TPB) ? tmpc[t + 1] : 0;
  float runl = (t + 1 < TPB) ? tmpl[t + 1] : 0.0f;
  for (int j = CH - 1; j >= 0; --j) {
    runc += c[t * CH + j]; runl += l[t * CH + j];
    c[t * CH + j] = runc;  l[t * CH + j] = runl;
  }
  __syncthreads();
}

// max b in [0,M) with scanned[b] >= r
__device__ int find_cut(const int* sc, int M, int r, int* ctrl) {
  __syncthreads();
  if (threadIdx.x == 0) *ctrl = -1;
  __syncthreads();
  int loc = -1;
  for (int i = threadIdx.x; i < M; i += blockDim.x)
    if (sc[i] >= r) loc = i;
  if (loc >= 0) atomicMax(ctrl, loc);
  __syncthreads();
  return *ctrl;
}

// overflow fallback: stream a whole row, histogram bin b1 (b2<0: bits[20:10]; else bits[9:0] of b2)
__device__ void stream_row_bin(const float* __restrict__ pred, const float* __restrict__ label,
                               int row, int b1, int b2, int* hcnt, float* hloss) {
  const size_t base = (size_t)row * N_COLS;
  const float4* p4 = reinterpret_cast<const float4*>(pred + base);
  const float4* l4 = reinterpret_cast<const float4*>(label + base);
  for (int it = 0; it < N_COLS / (TPB * 4); ++it) {
    const float4 pv = p4[it * TPB + threadIdx.x];
    const float4 lv = l4[it * TPB + threadIdx.x];
    const float xs[4] = {pv.x, pv.y, pv.z, pv.w};
    const float ys[4] = {lv.x, lv.y, lv.z, lv.w};
#pragma unroll
    for (int j = 0; j < 4; ++j) {
      if (ys[j] > 0.5f) continue;
      const unsigned key = key_from_pred(xs[j]);
      if ((int)(key >> 21) != b1) continue;
      if (b2 < 0) {
        atomicAdd(&hcnt[(key >> 10) & 0x7FF], 1);
        atomicAdd(&hloss[(key >> 10) & 0x7FF], neg_loss(xs[j]));
      } else {
        if ((int)((key >> 10) & 0x7FF) != b2) continue;
        atomicAdd(&hcnt[key & 0x3FF], 1);
        atomicAdd(&hloss[key & 0x3FF], neg_loss(xs[j]));
      }
    }
  }
}

// =====================  single fused cooperative kernel  =====================
__global__ __launch_bounds__(TPB, 4)
void fused_all(const float* __restrict__ pred, const float* __restrict__ label,
               int* __restrict__ slabCnt, int* __restrict__ slabNP, float* __restrict__ slabSP,
               int* __restrict__ numPos, float* __restrict__ SPosArr,
               int* __restrict__ candBin, unsigned long long* __restrict__ auto64,
               int* __restrict__ r1Arr, int* __restrict__ kArr,
               int* __restrict__ candCnt, float* __restrict__ S_above,
               unsigned* __restrict__ candList,
               double* __restrict__ gNum, int* __restrict__ gDen,
               float* __restrict__ out)
{
  cg::grid_group grid = cg::this_grid();
  __shared__ __align__(16) char smem[26624];
  int*      h_cnt  = (int*)smem;                 // [2048]
  float*    h_loss = (float*)(smem + 8192);      // [2048]
  int*      r3c    = (int*)(smem + 16384);       // [1024]
  float*    r3l    = (float*)(smem + 20480);     // [1024]
  int*      tmpc   = (int*)(smem + 24576);       // [256]
  float*    tmpl   = (float*)(smem + 25600);     // [256]
  unsigned* candSh = (unsigned*)smem;            // [4096] P3 only (overlaps)
  __shared__ int   s_ctrl, s_bcast, s_base;
  __shared__ int   wnp[TPB / 64];
  __shared__ float wsp[TPB / 64];

  const int tid = threadIdx.x;
  const int lane = tid & 63, wid = tid >> 6;

  // ---------------- P1: per-vb count hist + pos stats ----------------
  for (int vb = blockIdx.x; vb < VB1; vb += gridDim.x) {
    for (int i = tid; i < 2048; i += TPB) h_cnt[i] = 0;
    __syncthreads();
    const size_t base = (size_t)vb * SEG_ELEMS;
    const float4* p4 = reinterpret_cast<const float4*>(pred + base);
    const float4* l4 = reinterpret_cast<const float4*>(label + base);
    int npos = 0; float spos = 0.0f;
    for (int it = 0; it < ITERS; ++it) {
      const float4 pv = p4[it * TPB + tid];
      const float4 lv = l4[it * TPB + tid];
      const float xs[4] = {pv.x, pv.y, pv.z, pv.w};
      const float ys[4] = {lv.x, lv.y, lv.z, lv.w};
#pragma unroll
      for (int j = 0; j < 4; ++j) {
        if (ys[j] > 0.5f) { npos += 1; spos += pos_loss(xs[j]); }
        else atomicAdd(&h_cnt[key_from_pred(xs[j]) >> 21], 1);
      }
    }
#pragma unroll
    for (int off = 32; off > 0; off >>= 1) {
      npos += __shfl_down(npos, off);
      spos += __shfl_down(spos, off);
    }
    if (lane == 0) { wnp[wid] = npos; wsp[wid] = spos; }
    __syncthreads();
    if (tid == 0) {
      int tn = 0; float ts = 0.0f;
      for (int i = 0; i < TPB / 64; ++i) { tn += wnp[i]; ts += wsp[i]; }
      slabNP[vb] = tn; slabSP[vb] = ts;
    }
    for (int i = tid; i < 2048; i += TPB) slabCnt[(size_t)vb * 2048 + i] = h_cnt[i];
    __syncthreads();
  }
  grid.sync();

  // ---------------- P2: per-row cutoff + zero row state ----------------
  for (int row = blockIdx.x; row < B_ROWS; row += gridDim.x) {
    for (int i = tid; i < 2048; i += TPB) {
      int v = 0;
#pragma unroll
      for (int s = 0; s < SEGS; ++s) v += slabCnt[(size_t)(row * SEGS + s) * 2048 + i];
      h_cnt[i] = v; h_loss[i] = 0.0f;
    }
    if (tid == 0) {
      int tn = 0; float ts = 0.0f;
      for (int s = 0; s < SEGS; ++s) { tn += slabNP[row * SEGS + s]; ts += slabSP[row * SEGS + s]; }
      s_bcast = tn; wsp[0] = ts;
    }
    __syncthreads();
    const int np = s_bcast;
    const float sp = wsp[0];
    const int nneg = N_COLS - np;
    const int k = (3 * np < nneg) ? 3 * np : nneg;
    suffix_scan_2l(h_cnt, h_loss, 2048, tmpc, tmpl);
    int b1 = -1, r1 = 0; unsigned long long at = 1ull << 32;
    if (k > 0) {
      b1 = find_cut(h_cnt, 2048, k, &s_ctrl);
      const int above = (b1 + 1 < 2048) ? h_cnt[b1 + 1] : 0;
      r1 = k - above;
      at = (unsigned long long)(b1 + 1) << 21;
    }
    if (tid == 0) {
      numPos[row] = np; SPosArr[row] = sp;
      candBin[row] = b1; auto64[row] = at; r1Arr[row] = r1; kArr[row] = k;
      candCnt[row] = 0; S_above[row] = 0.0f;
    }
    __syncthreads();
  }
  if (blockIdx.x == 0 && tid == 0) { *gNum = 0.0; *gDen = 0; }
  grid.sync();

  // ---------------- P3: auto-loss + candidate gather (recompute keys; pred/label L3-hot) ----
  for (int vb = blockIdx.x; vb < VB1; vb += gridDim.x) {
    const int row = vb / SEGS;
    const int cb = candBin[row];
    const unsigned long long at = auto64[row];
    if (tid == 0) s_bcast = 0;
    __syncthreads();
    const size_t base = (size_t)vb * SEG_ELEMS;
    const float4* p4 = reinterpret_cast<const float4*>(pred + base);
    const float4* l4 = reinterpret_cast<const float4*>(label + base);
    float acc = 0.0f;
    for (int it = 0; it < ITERS; ++it) {
      const float4 pv = p4[it * TPB + tid];
      const float4 lv = l4[it * TPB + tid];
      const float xs[4] = {pv.x, pv.y, pv.z, pv.w};
      const float ys[4] = {lv.x, lv.y, lv.z, lv.w};
#pragma unroll
      for (int j = 0; j < 4; ++j) {
        if (ys[j] > 0.5f) continue;
        const unsigned key = key_from_pred(xs[j]);
        if ((unsigned long long)key >= at) {
          acc += neg_loss(xs[j]);
        } else if ((int)(key >> 21) == cb) {
          const int idx = atomicAdd(&s_bcast, 1);
          if (idx < CAND_SH) candSh[idx] = key;   // counted even if clipped -> fallback safe
        }
      }
    }
#pragma unroll
    for (int off = 32; off > 0; off >>= 1) acc += __shfl_down(acc, off);
    if (lane == 0) wsp[wid] = acc;
    __syncthreads();
    if (tid == 0) {
      float t = 0.0f;
      for (int i = 0; i < TPB / 64; ++i) t += wsp[i];
      unsafeAtomicAdd(&S_above[row], t);
      s_base = atomicAdd(&candCnt[row], s_bcast);   // one global atomic per vb
    }
    __syncthreads();
    const int cnt = (s_bcast < CAND_SH) ? s_bcast : CAND_SH;
    const int gb = s_base;
    for (int i = tid; i < cnt; i += TPB) {
      const int g = gb + i;
      if (g < CAP) candList[(size_t)row * CAP + g] = candSh[i];
    }
    __syncthreads();
  }
  grid.sync();

  // ---------------- P4: per-row refine (two-pass, no key cache) ----------------
  for (int row = blockIdx.x; row < B_ROWS; row += gridDim.x) {
    const int k = kArr[row];
    float S = 0.0f;
    if (k > 0) {
      const int r1 = r1Arr[row], b1 = candBin[row], cc = candCnt[row];
      for (int i = tid; i < 2048; i += TPB) { h_cnt[i] = 0; h_loss[i] = 0.0f; }
      __syncthreads();
      if (cc <= CAP) {
        for (int i = tid; i < cc; i += TPB) {
          const unsigned key = candList[(size_t)row * CAP + i];
          const float l = loss_from_key(key);
          atomicAdd(&h_cnt[(key >> 10) & 0x7FF], 1);
          atomicAdd(&h_loss[(key >> 10) & 0x7FF], l);
        }
      } else {
        stream_row_bin(pred, label, row, b1, -1, h_cnt, h_loss);
      }
      __syncthreads();
      suffix_scan_2l(h_cnt, h_loss, 2048, tmpc, tmpl);
      const int b2 = find_cut(h_cnt, 2048, r1, &s_ctrl);
      const int r2 = r1 - ((b2 + 1 < 2048) ? h_cnt[b2 + 1] : 0);
      S += (b2 + 1 < 2048) ? h_loss[b2 + 1] : 0.0f;
      __syncthreads();
      for (int i = tid; i < 1024; i += TPB) { r3c[i] = 0; r3l[i] = 0.0f; }
      __syncthreads();
      if (cc <= CAP) {
        for (int i = tid; i < cc; i += TPB) {
          const unsigned key = candList[(size_t)row * CAP + i];
          if ((int)((key >> 10) & 0x7FF) == b2) {
            atomicAdd(&r3c[key & 0x3FF], 1);
            atomicAdd(&r3l[key & 0x3FF], loss_from_key(key));
          }
        }
      } else {
        stream_row_bin(pred, label, row, b1, b2, r3c, r3l);
      }
      __syncthreads();
      for (int i = tid; i < 1024; i += TPB) { h_cnt[i] = r3c[i]; h_loss[i] = r3l[i]; }
      __syncthreads();
      suffix_scan_2l(h_cnt, h_loss, 1024, tmpc, tmpl);
      const int b3 = find_cut(h_cnt, 1024, r2, &s_ctrl);
      const int r3 = r2 - ((b3 + 1 < 1024) ? h_cnt[b3 + 1] : 0);
      S += (b3 + 1 < 1024) ? h_loss[b3 + 1] : 0.0f;
      S += (float)r3 * (r3l[b3] / (float)r3c[b3]);    // exact-key ties
    }
    if (tid == 0) {
      const double contrib = (double)SPosArr[row] +
                             (k > 0 ? (double)S + (double)S_above[row] : 0.0);
      unsafeAtomicAdd(gNum, contrib);
      atomicAdd(gDen, numPos[row] + (k > 0 ? k : 0));
    }
    __syncthreads();
  }
  grid.sync();

  // ---------------- P5: final write ----------------
  if (blockIdx.x == 0 && tid == 0) {
    const double num = unsafeAtomicAdd(gNum, 0.0);
    const int    den = atomicAdd(gDen, 0);
    out[0] = (float)(num / (double)den);
  }
}

// =======================  host launcher  =======================
extern "C" void kernel_launch(void* const* d_in, const int* in_sizes, int n_in,
                              void* d_out, int out_size, void* d_ws, size_t ws_size,
                              hipStream_t stream)
{
  const float* pred  = (const float*)d_in[0];
  const float* label = (const float*)d_in[1];
  float* out = (float*)d_out;
  char* ws = (char*)d_ws;

  int*      slabCnt = (int*)(ws + OFF_SLABCNT);
  int*      slabNP  = (int*)(ws + OFF_SLABNP);
  float*    slabSP  = (float*)(ws + OFF_SLABSP);
  unsigned* cand    = (unsigned*)(ws + OFF_CAND);
  char*     misc    = ws + OFF_MISC;
  int*      numPos  = (int*)(misc + MO_NUMPOS);
  float*    SPos    = (float*)(misc + MO_SPOS);
  int*      candBin = (int*)(misc + MO_CANDBIN);
  int*      r1Arr   = (int*)(misc + MO_R1);
  int*      kArr    = (int*)(misc + MO_KARR);
  int*      candCnt = (int*)(misc + MO_CANDCNT);
  float*    S_above = (float*)(misc + MO_SABOVE);
  unsigned long long* auto64 = (unsigned long long*)(misc + MO_AUTO64);
  double*   gNum    = (double*)(misc + MO_GNUM);
  int*      gDen    = (int*)(misc + MO_GDEN);

  // size grid to guaranteed co-residency (cooperative launch requirement)
  int maxB = 0;
  if (hipOccupancyMaxActiveBlocksPerMultiprocessor(&maxB, fused_all, TPB, 0) != hipSuccess || maxB < 1)
    maxB = 4;   // conservative: 27KB LDS + <=128 VGPR -> 4 blocks/CU on gfx950
  long long grid_ll = (long long)maxB * 256;   // 256 CUs on MI355X
  if (grid_ll > VB1) grid_ll = VB1;
  dim3 grid((unsigned)grid_ll), block(TPB);

  void* args[] = {
    (void*)&pred, (void*)&label,
    (void*)&slabCnt, (void*)&slabNP, (void*)&slabSP,
    (void*)&numPos, (void*)&SPos,
    (void*)&candBin, (void*)&auto64, (void*)&r1Arr, (void*)&kArr,
    (void*)&candCnt, (void*)&S_above, (void*)&cand,
    (void*)&gNum, (void*)&gDen, (void*)&out
  };
  hipLaunchCooperativeKernel(reinterpret_cast<void*>(fused_all), grid, block, args, 0, stream);
}

// Round 12
// 346.006 us; speedup vs baseline: 1.7437x; 1.7437x over previous
//
#include <hip/hip_runtime.h>
#include <cstdint>
#include <cstddef>

constexpr int B_ROWS = 128;
constexpr int N_COLS = 65536;
constexpr int CAP    = 4096;        // per-row candidate capacity (expected ~1.8k)
constexpr int TPB    = 256;
constexpr int VB1    = 1024;        // virtual blocks (8 per row)
constexpr int SEGS   = VB1 / B_ROWS;            // 8
constexpr int SEG_ELEMS = N_COLS / SEGS;        // 8192
constexpr int ITERS  = SEG_ELEMS / (TPB * 4);   // 8
constexpr int CAND_SH = 4096;

// ---- ws layout (bytes); [0, 1MB+8KB) is memset to 0 each call ----
constexpr size_t OFF_HISTG = 0;                  // int[128][2048]  1MB (atomic hist)
constexpr size_t OFF_MISC  = (size_t)1 << 20;    // control block (8KB)
constexpr size_t MO_ROW1D  = 0;      // int[128]  phase-1 done counters
constexpr size_t MO_FLAG   = 512;    // int[128]  cutoff-ready flag (0=not ready; 1=k<=0; else b1+2)
constexpr size_t MO_ROW2D  = 1024;   // int[128]  phase-2 done counters
constexpr size_t MO_CCNT   = 1536;   // int[128]  candidate counts
constexpr size_t MO_NPOS   = 2048;   // int[128]
constexpr size_t MO_SPOS   = 2560;   // float[128]
constexpr size_t MO_SABV   = 3072;   // float[128]
constexpr size_t MO_GNUM   = 3584;   // double
constexpr size_t MO_GDEN   = 3592;   // int
constexpr size_t MO_GDONE  = 3596;   // int
constexpr size_t MO_R1     = 4096;   // int[128]
constexpr size_t MO_KARR   = 4608;   // int[128]
constexpr size_t MISC_BYTES= 8192;
constexpr size_t OFF_CAND  = (size_t)2 << 20;    // uint[128][4096]  2MB (no pre-zero)

#define SCOPE __HIP_MEMORY_SCOPE_AGENT

// ---- monotone key <-> pred ----
__device__ __forceinline__ unsigned key_from_pred(float x) {
  unsigned b = __float_as_uint(x);
  return (b & 0x80000000u) ? ~b : (b | 0x80000000u);
}
__device__ __forceinline__ float pred_from_key(unsigned k) {
  unsigned b = (k & 0x80000000u) ? (k ^ 0x80000000u) : ~k;
  return __uint_as_float(b);
}

// ---- elementwise losses (validated absmax=0.0 R1/R3/R5/R8/R10) ----
__device__ __forceinline__ float neg_loss(float x) {
  float ax = fabsf(x);
  float e  = expf(-ax);
  float p  = (x >= 0.0f) ? 1.0f / (1.0f + e) : e / (1.0f + e);
  float sp = fmaxf(x, 0.0f) + log1pf(e);
  float f  = p;
  float l  = sp * f * f * 0.25f;
  return (p >= 0.5f) ? l * 3.0f : l;
}
__device__ __forceinline__ float pos_loss(float x) {
  float ax = fabsf(x);
  float e  = expf(-ax);
  float p  = (x >= 0.0f) ? 1.0f / (1.0f + e) : e / (1.0f + e);
  float sp = fmaxf(-x, 0.0f) + log1pf(e);
  float f  = 1.0f - p;
  float l  = sp * f * f * 0.75f;
  return (p < 0.5f) ? l * 3.0f : l;
}
__device__ __forceinline__ float loss_from_key(unsigned k) { return neg_loss(pred_from_key(k)); }

// ---- two-level inclusive suffix scan over M = CH*TPB bins (validated R10) ----
__device__ void suffix_scan_2l(int* c, float* l, int M, int* tmpc, float* tmpl) {
  const int t = threadIdx.x;
  const int CH = M / TPB;
  int cs = 0; float ls = 0.0f;
  for (int j = 0; j < CH; ++j) { cs += c[t * CH + j]; ls += l[t * CH + j]; }
  tmpc[t] = cs; tmpl[t] = ls;
  __syncthreads();
  for (int d = 1; d < TPB; d <<= 1) {
    int v = tmpc[t] + ((t + d < TPB) ? tmpc[t + d] : 0);
    float w = tmpl[t] + ((t + d < TPB) ? tmpl[t + d] : 0.0f);
    __syncthreads();
    tmpc[t] = v; tmpl[t] = w;
    __syncthreads();
  }
  int runc = (t + 1 < TPB) ? tmpc[t + 1] : 0;
  float runl = (t + 1 < TPB) ? tmpl[t + 1] : 0.0f;
  for (int j = CH - 1; j >= 0; --j) {
    runc += c[t * CH + j]; runl += l[t * CH + j];
    c[t * CH + j] = runc;  l[t * CH + j] = runl;
  }
  __syncthreads();
}

__device__ int find_cut(const int* sc, int M, int r, int* ctrl) {
  __syncthreads();
  if (threadIdx.x == 0) *ctrl = -1;
  __syncthreads();
  int loc = -1;
  for (int i = threadIdx.x; i < M; i += blockDim.x)
    if (sc[i] >= r) loc = i;
  if (loc >= 0) atomicMax(ctrl, loc);
  __syncthreads();
  return *ctrl;
}

// overflow fallback: stream whole row for bin b1 (b2<0: bits[20:10]; else bits[9:0])
__device__ void stream_row_bin(const float* __restrict__ pred, const float* __restrict__ label,
                               int row, int b1, int b2, int* hcnt, float* hloss) {
  const size_t base = (size_t)row * N_COLS;
  const float4* p4 = reinterpret_cast<const float4*>(pred + base);
  const float4* l4 = reinterpret_cast<const float4*>(label + base);
  for (int it = 0; it < N_COLS / (TPB * 4); ++it) {
    const float4 pv = p4[it * TPB + threadIdx.x];
    const float4 lv = l4[it * TPB + threadIdx.x];
    const float xs[4] = {pv.x, pv.y, pv.z, pv.w};
    const float ys[4] = {lv.x, lv.y, lv.z, lv.w};
#pragma unroll
    for (int j = 0; j < 4; ++j) {
      if (ys[j] > 0.5f) continue;
      const unsigned key = key_from_pred(xs[j]);
      if ((int)(key >> 21) != b1) continue;
      if (b2 < 0) {
        atomicAdd(&hcnt[(key >> 10) & 0x7FF], 1);
        atomicAdd(&hloss[(key >> 10) & 0x7FF], neg_loss(xs[j]));
      } else {
        if ((int)((key >> 10) & 0x7FF) != b2) continue;
        atomicAdd(&hcnt[key & 0x3FF], 1);
        atomicAdd(&hloss[key & 0x3FF], neg_loss(xs[j]));
      }
    }
  }
}

// ==========  single fused kernel: per-row dataflow, NO grid.sync  ==========
__global__ __launch_bounds__(TPB, 4)
void fused_flow(const float* __restrict__ pred, const float* __restrict__ label,
                int* __restrict__ histG,
                int* __restrict__ row1done, int* __restrict__ flagArr, int* __restrict__ row2done,
                int* __restrict__ candCnt, int* __restrict__ numPos,
                float* __restrict__ SPos, float* __restrict__ S_above,
                int* __restrict__ r1Arr, int* __restrict__ kArr,
                unsigned* __restrict__ candList,
                double* __restrict__ gNum, int* __restrict__ gDen, int* __restrict__ gDone,
                float* __restrict__ out)
{
  __shared__ __align__(16) char smem[26624];
  int*      h_cnt  = (int*)smem;                 // [2048]
  float*    h_loss = (float*)(smem + 8192);      // [2048]
  int*      r3c    = (int*)(smem + 16384);       // [1024]
  float*    r3l    = (float*)(smem + 20480);     // [1024]
  int*      tmpc   = (int*)(smem + 24576);       // [256]
  float*    tmpl   = (float*)(smem + 25600);     // [256]
  unsigned* candSh = (unsigned*)smem;            // [4096] phase-2 only (overlays)
  __shared__ int   s_ctrl, s_cnt, s_base, s_flag;
  __shared__ int   wnp[TPB / 64];
  __shared__ float wsp[TPB / 64];
  __shared__ int   s_last1, s_last2;

  const int tid = threadIdx.x;
  const int lane = tid & 63, wid = tid >> 6;

  // =============== phase 1: per-vb hist -> global row hist; last-of-row computes cutoff ======
  for (int vb = blockIdx.x; vb < VB1; vb += gridDim.x) {
    const int row = vb / SEGS;
    for (int i = tid; i < 2048; i += TPB) h_cnt[i] = 0;
    __syncthreads();
    const size_t base = (size_t)vb * SEG_ELEMS;
    const float4* p4 = reinterpret_cast<const float4*>(pred + base);
    const float4* l4 = reinterpret_cast<const float4*>(label + base);
    int npos = 0; float spos = 0.0f;
    for (int it = 0; it < ITERS; ++it) {
      const float4 pv = p4[it * TPB + tid];
      const float4 lv = l4[it * TPB + tid];
      const float xs[4] = {pv.x, pv.y, pv.z, pv.w};
      const float ys[4] = {lv.x, lv.y, lv.z, lv.w};
#pragma unroll
      for (int j = 0; j < 4; ++j) {
        if (ys[j] > 0.5f) { npos += 1; spos += pos_loss(xs[j]); }
        else atomicAdd(&h_cnt[key_from_pred(xs[j]) >> 21], 1);
      }
    }
#pragma unroll
    for (int off = 32; off > 0; off >>= 1) {
      npos += __shfl_down(npos, off);
      spos += __shfl_down(spos, off);
    }
    if (lane == 0) { wnp[wid] = npos; wsp[wid] = spos; }
    __syncthreads();
    if (tid == 0) {
      int tn = 0; float ts = 0.0f;
      for (int i = 0; i < TPB / 64; ++i) { tn += wnp[i]; ts += wsp[i]; }
      atomicAdd(&numPos[row], tn);
      unsafeAtomicAdd(&SPos[row], ts);
    }
    // merge LDS hist into global row hist (coherent atomics; bins are sparse)
    for (int i = tid; i < 2048; i += TPB)
      if (h_cnt[i]) atomicAdd(&histG[row * 2048 + i], h_cnt[i]);
    __syncthreads();             // RACE FIX (R11 audit): whole block's merge done before publish
    if (tid == 0) {
      __threadfence();
      const int pos = __hip_atomic_fetch_add(&row1done[row], 1, __ATOMIC_ACQ_REL, SCOPE);
      s_last1 = (pos == SEGS - 1);
      if (s_last1) __threadfence();
    }
    __syncthreads();
    if (s_last1) {
      // --- cutoff tail for this row ---
      for (int i = tid; i < 2048; i += TPB) {
        h_cnt[i]  = __hip_atomic_load(&histG[row * 2048 + i], __ATOMIC_RELAXED, SCOPE);
        h_loss[i] = 0.0f;
      }
      __syncthreads();
      int np;
      if (tid == 0) { s_cnt = __hip_atomic_fetch_add(&numPos[row], 0, __ATOMIC_RELAXED, SCOPE); }
      __syncthreads();
      np = s_cnt;
      const int nneg = N_COLS - np;
      const int k = (3 * np < nneg) ? 3 * np : nneg;
      suffix_scan_2l(h_cnt, h_loss, 2048, tmpc, tmpl);
      int b1 = -1, r1 = 0;
      if (k > 0) {
        b1 = find_cut(h_cnt, 2048, k, &s_ctrl);
        r1 = k - ((b1 + 1 < 2048) ? h_cnt[b1 + 1] : 0);
      }
      if (tid == 0) {
        r1Arr[row] = r1;
        kArr[row]  = k;
        // release: publish cutoff (flag encodes b1; 1 means k<=0)
        __hip_atomic_store(&flagArr[row], (k > 0) ? (b1 + 2) : 1, __ATOMIC_RELEASE, SCOPE);
      }
      __syncthreads();
    }
  }

  // =============== phase 2: spin own row's flag; auto-loss + candidate gather ======
  for (int vb = blockIdx.x; vb < VB1; vb += gridDim.x) {
    const int row = vb / SEGS;
    if (tid == 0) {
      int f;
      do { f = __hip_atomic_load(&flagArr[row], __ATOMIC_ACQUIRE, SCOPE); } while (f == 0);
      s_flag = f;
    }
    __syncthreads();
    const int f = s_flag;
    if (f > 1) {
      const int cb = f - 2;
      const unsigned long long at = (unsigned long long)(cb + 1) << 21;
      if (tid == 0) s_cnt = 0;
      __syncthreads();
      const size_t base = (size_t)vb * SEG_ELEMS;
      const float4* p4 = reinterpret_cast<const float4*>(pred + base);
      const float4* l4 = reinterpret_cast<const float4*>(label + base);
      float acc = 0.0f;
      for (int it = 0; it < ITERS; ++it) {
        const float4 pv = p4[it * TPB + tid];
        const float4 lv = l4[it * TPB + tid];
        const float xs[4] = {pv.x, pv.y, pv.z, pv.w};
        const float ys[4] = {lv.x, lv.y, lv.z, lv.w};
#pragma unroll
        for (int j = 0; j < 4; ++j) {
          if (ys[j] > 0.5f) continue;
          const unsigned key = key_from_pred(xs[j]);
          if ((unsigned long long)key >= at) {
            acc += neg_loss(xs[j]);
          } else if ((int)(key >> 21) == cb) {
            const int idx = atomicAdd(&s_cnt, 1);
            if (idx < CAND_SH) candSh[idx] = key;   // counted even if clipped
          }
        }
      }
#pragma unroll
      for (int off = 32; off > 0; off >>= 1) acc += __shfl_down(acc, off);
      if (lane == 0) wsp[wid] = acc;
      __syncthreads();
      if (tid == 0) {
        float t = 0.0f;
        for (int i = 0; i < TPB / 64; ++i) t += wsp[i];
        unsafeAtomicAdd(&S_above[row], t);
        s_base = atomicAdd(&candCnt[row], s_cnt);   // one global atomic per block
      }
      __syncthreads();
      const int cnt = (s_cnt < CAND_SH) ? s_cnt : CAND_SH;
      const int gb = s_base;
      for (int i = tid; i < cnt; i += TPB) {
        const int g = gb + i;
        if (g < CAP) candList[(size_t)row * CAP + g] = candSh[i];
      }
    }
    __syncthreads();             // RACE FIX (R11 audit): candList copy done before publish
    if (tid == 0) {
      __threadfence();
      const int pos = __hip_atomic_fetch_add(&row2done[row], 1, __ATOMIC_ACQ_REL, SCOPE);
      s_last2 = (pos == SEGS - 1);
      if (s_last2) __threadfence();
    }
    __syncthreads();

    if (!s_last2) continue;

    // =============== phase 3: refine tail for this row ======
    const int row_ = row;
    int k, r1, cc, b1;
    if (tid == 0) {
      s_cnt  = kArr[row_];
      s_base = r1Arr[row_];
      s_ctrl = __hip_atomic_fetch_add(&candCnt[row_], 0, __ATOMIC_RELAXED, SCOPE);
      s_flag = (s_flag > 1) ? (s_flag - 2) : -1;
    }
    __syncthreads();
    k = s_cnt; r1 = s_base; cc = s_ctrl; b1 = s_flag;
    __syncthreads();
    float S = 0.0f;
    if (k > 0) {
      for (int i = tid; i < 2048; i += TPB) { h_cnt[i] = 0; h_loss[i] = 0.0f; }
      __syncthreads();
      if (cc <= CAP) {
        for (int i = tid; i < cc; i += TPB) {
          const unsigned key = __hip_atomic_load(&candList[(size_t)row_ * CAP + i], __ATOMIC_RELAXED, SCOPE);
          const float l = loss_from_key(key);
          atomicAdd(&h_cnt[(key >> 10) & 0x7FF], 1);
          atomicAdd(&h_loss[(key >> 10) & 0x7FF], l);
        }
      } else {
        stream_row_bin(pred, label, row_, b1, -1, h_cnt, h_loss);
      }
      __syncthreads();
      suffix_scan_2l(h_cnt, h_loss, 2048, tmpc, tmpl);
      const int b2 = find_cut(h_cnt, 2048, r1, &s_ctrl);
      const int r2 = r1 - ((b2 + 1 < 2048) ? h_cnt[b2 + 1] : 0);
      S += (b2 + 1 < 2048) ? h_loss[b2 + 1] : 0.0f;
      __syncthreads();
      for (int i = tid; i < 1024; i += TPB) { r3c[i] = 0; r3l[i] = 0.0f; }
      __syncthreads();
      if (cc <= CAP) {
        for (int i = tid; i < cc; i += TPB) {
          const unsigned key = __hip_atomic_load(&candList[(size_t)row_ * CAP + i], __ATOMIC_RELAXED, SCOPE);
          if ((int)((key >> 10) & 0x7FF) == b2) {
            atomicAdd(&r3c[key & 0x3FF], 1);
            atomicAdd(&r3l[key & 0x3FF], loss_from_key(key));
          }
        }
      } else {
        stream_row_bin(pred, label, row_, b1, b2, r3c, r3l);
      }
      __syncthreads();
      for (int i = tid; i < 1024; i += TPB) { h_cnt[i] = r3c[i]; h_loss[i] = r3l[i]; }
      __syncthreads();
      suffix_scan_2l(h_cnt, h_loss, 1024, tmpc, tmpl);
      const int b3 = find_cut(h_cnt, 1024, r2, &s_ctrl);
      const int r3 = r2 - ((b3 + 1 < 1024) ? h_cnt[b3 + 1] : 0);
      S += (b3 + 1 < 1024) ? h_loss[b3 + 1] : 0.0f;
      S += (float)r3 * (r3l[b3] / (float)r3c[b3]);    // exact-key ties (r3c[b3]>=r3>=1 by maximality)
    }
    if (tid == 0) {
      const int np = __hip_atomic_fetch_add(&numPos[row_], 0, __ATOMIC_RELAXED, SCOPE);
      const float sp = unsafeAtomicAdd(&SPos[row_], 0.0f);
      const float sa = (k > 0) ? unsafeAtomicAdd(&S_above[row_], 0.0f) : 0.0f;
      const double contrib = (double)sp + (k > 0 ? (double)S + (double)sa : 0.0);
      unsafeAtomicAdd(gNum, contrib);
      atomicAdd(gDen, np + (k > 0 ? k : 0));
      __threadfence();
      const int old = __hip_atomic_fetch_add(gDone, 1, __ATOMIC_ACQ_REL, SCOPE);
      if (old == B_ROWS - 1) {
        const double num = unsafeAtomicAdd(gNum, 0.0);
        const int    den = atomicAdd(gDen, 0);
        out[0] = (float)(num / (double)den);
      }
    }
    __syncthreads();
  }
}

// =======================  host launcher  =======================
extern "C" void kernel_launch(void* const* d_in, const int* in_sizes, int n_in,
                              void* d_out, int out_size, void* d_ws, size_t ws_size,
                              hipStream_t stream)
{
  const float* pred  = (const float*)d_in[0];
  const float* label = (const float*)d_in[1];
  float* out = (float*)d_out;
  char* ws = (char*)d_ws;

  int*      histG    = (int*)(ws + OFF_HISTG);
  char*     misc     = ws + OFF_MISC;
  int*      row1done = (int*)(misc + MO_ROW1D);
  int*      flagArr  = (int*)(misc + MO_FLAG);
  int*      row2done = (int*)(misc + MO_ROW2D);
  int*      candCnt  = (int*)(misc + MO_CCNT);
  int*      numPos   = (int*)(misc + MO_NPOS);
  float*    SPos     = (float*)(misc + MO_SPOS);
  float*    S_above  = (float*)(misc + MO_SABV);
  double*   gNum     = (double*)(misc + MO_GNUM);
  int*      gDen     = (int*)(misc + MO_GDEN);
  int*      gDone    = (int*)(misc + MO_GDONE);
  int*      r1Arr    = (int*)(misc + MO_R1);
  int*      kArr     = (int*)(misc + MO_KARR);
  unsigned* cand     = (unsigned*)(ws + OFF_CAND);

  // zero hist + control words (one small fill)
  hipMemsetAsync(ws, 0, OFF_MISC + MISC_BYTES, stream);

  // co-residency guarantee via cooperative launch (NO grid.sync inside)
  int maxB = 0;
  if (hipOccupancyMaxActiveBlocksPerMultiprocessor(&maxB, fused_flow, TPB, 0) != hipSuccess || maxB < 1)
    maxB = 4;
  long long grid_ll = (long long)maxB * 256;
  if (grid_ll > VB1) grid_ll = VB1;
  dim3 grid((unsigned)grid_ll), block(TPB);

  void* args[] = {
    (void*)&pred, (void*)&label, (void*)&histG,
    (void*)&row1done, (void*)&flagArr, (void*)&row2done,
    (void*)&candCnt, (void*)&numPos, (void*)&SPos, (void*)&S_above,
    (void*)&r1Arr, (void*)&kArr, (void*)&cand,
    (void*)&gNum, (void*)&gDen, (void*)&gDone, (void*)&out
  };
  hipLaunchCooperativeKernel(reinterpret_cast<void*>(fused_flow), grid, block, args, 0, stream);
}